// Round 2
// baseline (389.938 us; speedup 1.0000x reference)
//
#include <hip/hip_runtime.h>
#include <math.h>

namespace {
constexpr int   kB        = 8192;
constexpr int   kBlock    = 256;
constexpr int   kVec      = 4;
constexpr int   kChunks   = kB / (kBlock * kVec);   // 8 float4 per thread per row
constexpr float kMargin   = 0.1f;
constexpr float kThresh   = 0.5f;
constexpr float kScalePos = 2.0f;
constexpr float kScaleNeg = 40.0f;
constexpr float kEps      = 1e-5f;
}

// R5 == R4 resubmitted (previous round failed on container acquisition, not
// on the kernel). TLP instead of software pipelining: R3's 16 barriers/block
// each drain vmcnt(0) (gfx950 __syncthreads semantics), killing the prefetch
// pipeline, and its 64-VGPR double buffer capped the CU at 4 phase-coupled
// blocks. Here: one row per block (grid = 8192), 32 sim values per thread
// held in registers across both passes, only 2 barriers per block, and no
// double buffer -> VGPR <= 64 -> __launch_bounds__(256, 8) gives 8
// independent blocks/CU. Staggered independent blocks keep the memory pipe
// busy without any explicit prefetch. Labels (32 KB total) are L2-resident;
// per-block re-reads cost no HBM traffic. Label mask is built 2 int4 at a
// time under the sim-load shadow to keep peak registers ~56.
__global__ __launch_bounds__(kBlock, 8) void ms_loss_kernel(
    const float* __restrict__ sim,
    const int*   __restrict__ labels,
    float*       __restrict__ out)
{
  const int tid  = threadIdx.x;
  const int wave = tid >> 6;
  const int lane = tid & 63;
  const int row  = blockIdx.x;

  // ---- Issue the HBM-critical sim loads first ----
  const float* __restrict__ srow = sim + (size_t)row * kB;
  float4 v[kChunks];
  #pragma unroll
  for (int k = 0; k < kChunks; ++k)
    v[k] = *reinterpret_cast<const float4*>(srow + k * (kBlock * kVec) + tid * kVec);

  // ---- Same-class bitmask for this thread's 32 columns (under load shadow) ----
  const int ml = labels[row];                     // block-uniform -> s_load
  unsigned int m = 0u;
  #pragma unroll
  for (int k = 0; k < kChunks; k += 2) {
    const int4 la = *reinterpret_cast<const int4*>(labels + (k + 0) * (kBlock * kVec) + tid * kVec);
    const int4 lb = *reinterpret_cast<const int4*>(labels + (k + 1) * (kBlock * kVec) + tid * kVec);
    m |= (unsigned)(la.x == ml) << ((k + 0) * 4 + 0);
    m |= (unsigned)(la.y == ml) << ((k + 0) * 4 + 1);
    m |= (unsigned)(la.z == ml) << ((k + 0) * 4 + 2);
    m |= (unsigned)(la.w == ml) << ((k + 0) * 4 + 3);
    m |= (unsigned)(lb.x == ml) << ((k + 1) * 4 + 0);
    m |= (unsigned)(lb.y == ml) << ((k + 1) * 4 + 1);
    m |= (unsigned)(lb.z == ml) << ((k + 1) * 4 + 2);
    m |= (unsigned)(lb.w == ml) << ((k + 1) * 4 + 3);
  }

  __shared__ float s_min[kBlock / 64];
  __shared__ float s_max[kBlock / 64];
  __shared__ float s_pos[kBlock / 64];
  __shared__ float s_neg[kBlock / 64];

  // -- Pass 1 (registers): hardest positive / hardest negative --
  float min_pos =  INFINITY;
  float max_neg = -INFINITY;
  #pragma unroll
  for (int k = 0; k < kChunks; ++k) {
    const float4 f = v[k];
    const float xs[4] = {f.x, f.y, f.z, f.w};
    #pragma unroll
    for (int c = 0; c < 4; ++c) {
      const bool  same = (m >> (k * 4 + c)) & 1u;
      const float x = xs[c];
      min_pos = fminf(min_pos, (same && x < 1.0f - kEps) ? x : INFINITY);
      max_neg = fmaxf(max_neg, same ? -INFINITY : x);
    }
  }
  #pragma unroll
  for (int off = 32; off > 0; off >>= 1) {
    min_pos = fminf(min_pos, __shfl_xor(min_pos, off, 64));
    max_neg = fmaxf(max_neg, __shfl_xor(max_neg, off, 64));
  }
  if (lane == 0) { s_min[wave] = min_pos; s_max[wave] = max_neg; }
  __syncthreads();
  min_pos = fminf(fminf(s_min[0], s_min[1]), fminf(s_min[2], s_min[3]));
  max_neg = fmaxf(fmaxf(s_max[0], s_max[1]), fmaxf(s_max[2], s_max[3]));

  // -- Pass 2 (registers): mined exp-sums, one v_exp_f32 per element --
  // exp args in [-60, 20]: never underflows, so pos_sum>0 <=> any(sel_pos).
  float pos_sum = 0.0f, neg_sum = 0.0f;
  #pragma unroll
  for (int k = 0; k < kChunks; ++k) {
    const float4 f = v[k];
    const float xs[4] = {f.x, f.y, f.z, f.w};
    #pragma unroll
    for (int c = 0; c < 4; ++c) {
      const bool  same = (m >> (k * 4 + c)) & 1u;
      const float x = xs[c];
      const float a = same ? -kScalePos : kScaleNeg;
      const float e = __expf(a * (x - kThresh));
      const bool selp = same && (x < 1.0f - kEps) && (x - kMargin < max_neg);
      const bool seln = (!same) && (x + kMargin > min_pos);
      pos_sum += selp ? e : 0.0f;
      neg_sum += seln ? e : 0.0f;
    }
  }
  #pragma unroll
  for (int off = 32; off > 0; off >>= 1) {
    pos_sum += __shfl_xor(pos_sum, off, 64);
    neg_sum += __shfl_xor(neg_sum, off, 64);
  }
  if (lane == 0) { s_pos[wave] = pos_sum; s_neg[wave] = neg_sum; }
  __syncthreads();
  if (tid == 0) {
    pos_sum = (s_pos[0] + s_pos[1]) + (s_pos[2] + s_pos[3]);
    neg_sum = (s_neg[0] + s_neg[1]) + (s_neg[2] + s_neg[3]);
    if (pos_sum > 0.0f && neg_sum > 0.0f) {
      const float row_loss = log1pf(pos_sum) * (1.0f / kScalePos)
                           + log1pf(neg_sum) * (1.0f / kScaleNeg);
      atomicAdd(out, row_loss * (1.0f / (float)kB));
    }
  }
}

extern "C" void kernel_launch(void* const* d_in, const int* in_sizes, int n_in,
                              void* d_out, int out_size, void* d_ws, size_t ws_size,
                              hipStream_t stream) {
  const float* sim    = (const float*)d_in[0];
  const int*   labels = (const int*)d_in[1];
  float*       out    = (float*)d_out;

  // d_out is re-poisoned to 0xAA before every timed launch — zero it here.
  hipMemsetAsync(d_out, 0, sizeof(float) * (size_t)out_size, stream);
  ms_loss_kernel<<<dim3(kB), dim3(kBlock), 0, stream>>>(sim, labels, out);
}

// Round 3
// 378.273 us; speedup vs baseline: 1.0308x; 1.0308x over previous
//
#include <hip/hip_runtime.h>
#include <math.h>

namespace {
constexpr int   kB        = 8192;
constexpr int   kBlock    = 256;
constexpr int   kVec      = 4;
constexpr int   kChunks   = kB / (kBlock * kVec);   // 8 float4 per thread per row
constexpr float kMargin   = 0.1f;
constexpr float kThresh   = 0.5f;
constexpr float kScalePos = 2.0f;
constexpr float kScaleNeg = 40.0f;
constexpr float kEps      = 1e-5f;
}

// R6: kill the rematerialization. R5's counters: VGPR_Count=28 — too small to
// hold the 32 sim values, proving LLVM sank the (restrict-const) loads into
// BOTH passes: sim read twice (536 MB, second pass partially missing the
// exactly-sim-sized 256 MiB L3) + a second full load-wait after the barrier.
// Fix: after the 8 loads + mask build, pin every loaded component with
// asm volatile("" : "+v"(x)) — the asm output is a new value the compiler
// cannot re-derive from memory, forcing true register residency across both
// passes. __launch_bounds__(256, 6) (85-VGPR budget) guarantees the ~48-live
// peak fits with zero scratch; 24 waves/CU is still plenty of TLP for BW.
__global__ __launch_bounds__(kBlock, 6) void ms_loss_kernel(
    const float* __restrict__ sim,
    const int*   __restrict__ labels,
    float*       __restrict__ out)
{
  const int tid  = threadIdx.x;
  const int wave = tid >> 6;
  const int lane = tid & 63;
  const int row  = blockIdx.x;

  // ---- Issue the HBM-critical sim loads first (8 in flight) ----
  const float* __restrict__ srow = sim + (size_t)row * kB;
  float4 v[kChunks];
  #pragma unroll
  for (int k = 0; k < kChunks; ++k)
    v[k] = *reinterpret_cast<const float4*>(srow + k * (kBlock * kVec) + tid * kVec);

  // ---- Same-class bitmask for this thread's 32 columns (under load shadow) ----
  const int ml = labels[row];                     // block-uniform -> s_load
  unsigned int m = 0u;
  #pragma unroll
  for (int k = 0; k < kChunks; k += 2) {
    const int4 la = *reinterpret_cast<const int4*>(labels + (k + 0) * (kBlock * kVec) + tid * kVec);
    const int4 lb = *reinterpret_cast<const int4*>(labels + (k + 1) * (kBlock * kVec) + tid * kVec);
    m |= (unsigned)(la.x == ml) << ((k + 0) * 4 + 0);
    m |= (unsigned)(la.y == ml) << ((k + 0) * 4 + 1);
    m |= (unsigned)(la.z == ml) << ((k + 0) * 4 + 2);
    m |= (unsigned)(la.w == ml) << ((k + 0) * 4 + 3);
    m |= (unsigned)(lb.x == ml) << ((k + 1) * 4 + 0);
    m |= (unsigned)(lb.y == ml) << ((k + 1) * 4 + 1);
    m |= (unsigned)(lb.z == ml) << ((k + 1) * 4 + 2);
    m |= (unsigned)(lb.w == ml) << ((k + 1) * 4 + 3);
  }

  // ---- Pin the row in VGPRs: compiler can no longer re-load it in pass 2 ----
  #pragma unroll
  for (int k = 0; k < kChunks; ++k)
    asm volatile("" : "+v"(v[k].x), "+v"(v[k].y), "+v"(v[k].z), "+v"(v[k].w));

  __shared__ float s_min[kBlock / 64];
  __shared__ float s_max[kBlock / 64];
  __shared__ float s_pos[kBlock / 64];
  __shared__ float s_neg[kBlock / 64];

  // -- Pass 1 (registers): hardest positive / hardest negative --
  float min_pos =  INFINITY;
  float max_neg = -INFINITY;
  #pragma unroll
  for (int k = 0; k < kChunks; ++k) {
    const float4 f = v[k];
    const float xs[4] = {f.x, f.y, f.z, f.w};
    #pragma unroll
    for (int c = 0; c < 4; ++c) {
      const bool  same = (m >> (k * 4 + c)) & 1u;
      const float x = xs[c];
      min_pos = fminf(min_pos, (same && x < 1.0f - kEps) ? x : INFINITY);
      max_neg = fmaxf(max_neg, same ? -INFINITY : x);
    }
  }
  #pragma unroll
  for (int off = 32; off > 0; off >>= 1) {
    min_pos = fminf(min_pos, __shfl_xor(min_pos, off, 64));
    max_neg = fmaxf(max_neg, __shfl_xor(max_neg, off, 64));
  }
  if (lane == 0) { s_min[wave] = min_pos; s_max[wave] = max_neg; }
  __syncthreads();
  min_pos = fminf(fminf(s_min[0], s_min[1]), fminf(s_min[2], s_min[3]));
  max_neg = fmaxf(fmaxf(s_max[0], s_max[1]), fmaxf(s_max[2], s_max[3]));

  // -- Pass 2 (registers): mined exp-sums, one v_exp_f32 per element --
  // exp args in [-60, 20]: never underflows, so pos_sum>0 <=> any(sel_pos).
  float pos_sum = 0.0f, neg_sum = 0.0f;
  #pragma unroll
  for (int k = 0; k < kChunks; ++k) {
    const float4 f = v[k];
    const float xs[4] = {f.x, f.y, f.z, f.w};
    #pragma unroll
    for (int c = 0; c < 4; ++c) {
      const bool  same = (m >> (k * 4 + c)) & 1u;
      const float x = xs[c];
      const float a = same ? -kScalePos : kScaleNeg;
      const float e = __expf(a * (x - kThresh));
      const bool selp = same && (x < 1.0f - kEps) && (x - kMargin < max_neg);
      const bool seln = (!same) && (x + kMargin > min_pos);
      pos_sum += selp ? e : 0.0f;
      neg_sum += seln ? e : 0.0f;
    }
  }
  #pragma unroll
  for (int off = 32; off > 0; off >>= 1) {
    pos_sum += __shfl_xor(pos_sum, off, 64);
    neg_sum += __shfl_xor(neg_sum, off, 64);
  }
  if (lane == 0) { s_pos[wave] = pos_sum; s_neg[wave] = neg_sum; }
  __syncthreads();
  if (tid == 0) {
    pos_sum = (s_pos[0] + s_pos[1]) + (s_pos[2] + s_pos[3]);
    neg_sum = (s_neg[0] + s_neg[1]) + (s_neg[2] + s_neg[3]);
    if (pos_sum > 0.0f && neg_sum > 0.0f) {
      const float row_loss = log1pf(pos_sum) * (1.0f / kScalePos)
                           + log1pf(neg_sum) * (1.0f / kScaleNeg);
      atomicAdd(out, row_loss * (1.0f / (float)kB));
    }
  }
}

extern "C" void kernel_launch(void* const* d_in, const int* in_sizes, int n_in,
                              void* d_out, int out_size, void* d_ws, size_t ws_size,
                              hipStream_t stream) {
  const float* sim    = (const float*)d_in[0];
  const int*   labels = (const int*)d_in[1];
  float*       out    = (float*)d_out;

  // d_out is re-poisoned to 0xAA before every timed launch — zero it here.
  hipMemsetAsync(d_out, 0, sizeof(float) * (size_t)out_size, stream);
  ms_loss_kernel<<<dim3(kB), dim3(kBlock), 0, stream>>>(sim, labels, out);
}

// Round 4
// 355.553 us; speedup vs baseline: 1.0967x; 1.0639x over previous
//
#include <hip/hip_runtime.h>
#include <math.h>

namespace {
constexpr int   kB        = 8192;
constexpr int   kBlock    = 256;
constexpr int   kVec      = 4;
constexpr int   kChunks   = kB / (kBlock * kVec);   // 8 float4 per thread per row
constexpr float kMargin   = 0.1f;
constexpr float kThresh   = 0.5f;
constexpr float kScalePos = 2.0f;
constexpr float kScaleNeg = 40.0f;
constexpr float kEps      = 1e-5f;
}

// R7: kill the same-address atomic. R5's kernel counters showed FETCH=256KB +
// WRITE=256KB — sim is fully L3-resident (256 MiB = Infinity Cache size), so
// the kernel is NOT bandwidth-bound; the 512KB of HBM-visible traffic is the
// fingerprint of 8192 same-cacheline atomicAdd RMWs bouncing through the
// cross-XCD coherence point (~15-20ns each, serialized = 120-165us ~= the
// whole kernel time). Fix: each block plain-stores its row loss to ws[row]
// (fire-and-forget, no contention); a trivial second kernel reduces 8192
// floats (~5us). Atomic path kept as fallback if ws_size is too small.
// Register pinning from R6 retained (prevents the pass-2 re-read).
__global__ __launch_bounds__(kBlock, 6) void ms_loss_kernel(
    const float* __restrict__ sim,
    const int*   __restrict__ labels,
    float*       __restrict__ ws,      // nullptr -> atomic fallback
    float*       __restrict__ out)
{
  const int tid  = threadIdx.x;
  const int wave = tid >> 6;
  const int lane = tid & 63;
  const int row  = blockIdx.x;

  // ---- Issue the HBM/L3-critical sim loads first (8 in flight) ----
  const float* __restrict__ srow = sim + (size_t)row * kB;
  float4 v[kChunks];
  #pragma unroll
  for (int k = 0; k < kChunks; ++k)
    v[k] = *reinterpret_cast<const float4*>(srow + k * (kBlock * kVec) + tid * kVec);

  // ---- Same-class bitmask for this thread's 32 columns (under load shadow) ----
  const int ml = labels[row];                     // block-uniform -> s_load
  unsigned int m = 0u;
  #pragma unroll
  for (int k = 0; k < kChunks; k += 2) {
    const int4 la = *reinterpret_cast<const int4*>(labels + (k + 0) * (kBlock * kVec) + tid * kVec);
    const int4 lb = *reinterpret_cast<const int4*>(labels + (k + 1) * (kBlock * kVec) + tid * kVec);
    m |= (unsigned)(la.x == ml) << ((k + 0) * 4 + 0);
    m |= (unsigned)(la.y == ml) << ((k + 0) * 4 + 1);
    m |= (unsigned)(la.z == ml) << ((k + 0) * 4 + 2);
    m |= (unsigned)(la.w == ml) << ((k + 0) * 4 + 3);
    m |= (unsigned)(lb.x == ml) << ((k + 1) * 4 + 0);
    m |= (unsigned)(lb.y == ml) << ((k + 1) * 4 + 1);
    m |= (unsigned)(lb.z == ml) << ((k + 1) * 4 + 2);
    m |= (unsigned)(lb.w == ml) << ((k + 1) * 4 + 3);
  }

  // ---- Pin the row in VGPRs: compiler cannot re-load it in pass 2 ----
  #pragma unroll
  for (int k = 0; k < kChunks; ++k)
    asm volatile("" : "+v"(v[k].x), "+v"(v[k].y), "+v"(v[k].z), "+v"(v[k].w));

  __shared__ float s_min[kBlock / 64];
  __shared__ float s_max[kBlock / 64];
  __shared__ float s_pos[kBlock / 64];
  __shared__ float s_neg[kBlock / 64];

  // -- Pass 1 (registers): hardest positive / hardest negative --
  float min_pos =  INFINITY;
  float max_neg = -INFINITY;
  #pragma unroll
  for (int k = 0; k < kChunks; ++k) {
    const float4 f = v[k];
    const float xs[4] = {f.x, f.y, f.z, f.w};
    #pragma unroll
    for (int c = 0; c < 4; ++c) {
      const bool  same = (m >> (k * 4 + c)) & 1u;
      const float x = xs[c];
      min_pos = fminf(min_pos, (same && x < 1.0f - kEps) ? x : INFINITY);
      max_neg = fmaxf(max_neg, same ? -INFINITY : x);
    }
  }
  #pragma unroll
  for (int off = 32; off > 0; off >>= 1) {
    min_pos = fminf(min_pos, __shfl_xor(min_pos, off, 64));
    max_neg = fmaxf(max_neg, __shfl_xor(max_neg, off, 64));
  }
  if (lane == 0) { s_min[wave] = min_pos; s_max[wave] = max_neg; }
  __syncthreads();
  min_pos = fminf(fminf(s_min[0], s_min[1]), fminf(s_min[2], s_min[3]));
  max_neg = fmaxf(fmaxf(s_max[0], s_max[1]), fmaxf(s_max[2], s_max[3]));

  // -- Pass 2 (registers): mined exp-sums, one v_exp_f32 per element --
  // exp args in [-60, 20]: never underflows, so pos_sum>0 <=> any(sel_pos).
  float pos_sum = 0.0f, neg_sum = 0.0f;
  #pragma unroll
  for (int k = 0; k < kChunks; ++k) {
    const float4 f = v[k];
    const float xs[4] = {f.x, f.y, f.z, f.w};
    #pragma unroll
    for (int c = 0; c < 4; ++c) {
      const bool  same = (m >> (k * 4 + c)) & 1u;
      const float x = xs[c];
      const float a = same ? -kScalePos : kScaleNeg;
      const float e = __expf(a * (x - kThresh));
      const bool selp = same && (x < 1.0f - kEps) && (x - kMargin < max_neg);
      const bool seln = (!same) && (x + kMargin > min_pos);
      pos_sum += selp ? e : 0.0f;
      neg_sum += seln ? e : 0.0f;
    }
  }
  #pragma unroll
  for (int off = 32; off > 0; off >>= 1) {
    pos_sum += __shfl_xor(pos_sum, off, 64);
    neg_sum += __shfl_xor(neg_sum, off, 64);
  }
  if (lane == 0) { s_pos[wave] = pos_sum; s_neg[wave] = neg_sum; }
  __syncthreads();
  if (tid == 0) {
    pos_sum = (s_pos[0] + s_pos[1]) + (s_pos[2] + s_pos[3]);
    neg_sum = (s_neg[0] + s_neg[1]) + (s_neg[2] + s_neg[3]);
    const bool  valid    = (pos_sum > 0.0f) && (neg_sum > 0.0f);
    const float row_loss = valid ? (log1pf(pos_sum) * (1.0f / kScalePos)
                                  + log1pf(neg_sum) * (1.0f / kScaleNeg))
                                 : 0.0f;
    if (ws) {
      ws[row] = row_loss;                               // contention-free store
    } else if (row_loss != 0.0f) {
      atomicAdd(out, row_loss * (1.0f / (float)kB));    // fallback
    }
  }
}

// Sums ws[0..8191], scales by 1/B, writes out[0]. One block, ~32KB L2 read.
__global__ __launch_bounds__(256) void ms_reduce_kernel(
    const float* __restrict__ ws,
    float*       __restrict__ out)
{
  const int tid = threadIdx.x;
  float s = 0.0f;
  #pragma unroll
  for (int k = 0; k < 8; ++k) {
    const float4 f = *reinterpret_cast<const float4*>(ws + k * 1024 + tid * 4);
    s += (f.x + f.y) + (f.z + f.w);
  }
  #pragma unroll
  for (int off = 32; off > 0; off >>= 1)
    s += __shfl_xor(s, off, 64);
  __shared__ float sm[4];
  if ((tid & 63) == 0) sm[tid >> 6] = s;
  __syncthreads();
  if (tid == 0)
    out[0] = ((sm[0] + sm[1]) + (sm[2] + sm[3])) * (1.0f / (float)kB);
}

extern "C" void kernel_launch(void* const* d_in, const int* in_sizes, int n_in,
                              void* d_out, int out_size, void* d_ws, size_t ws_size,
                              hipStream_t stream) {
  const float* sim    = (const float*)d_in[0];
  const int*   labels = (const int*)d_in[1];
  float*       out    = (float*)d_out;

  // d_out is re-poisoned to 0xAA before every timed launch — zero it here
  // (also covers any padding bytes beyond out[0]).
  hipMemsetAsync(d_out, 0, sizeof(float) * (size_t)out_size, stream);

  if (d_ws != nullptr && ws_size >= (size_t)kB * sizeof(float)) {
    float* ws = (float*)d_ws;
    ms_loss_kernel<<<dim3(kB), dim3(kBlock), 0, stream>>>(sim, labels, ws, out);
    ms_reduce_kernel<<<dim3(1), dim3(256), 0, stream>>>(ws, out);
  } else {
    ms_loss_kernel<<<dim3(kB), dim3(kBlock), 0, stream>>>(sim, labels, nullptr, out);
  }
}